// Round 5
// baseline (229.765 us; speedup 1.0000x reference)
//
#include <hip/hip_runtime.h>

constexpr int TPB   = 256;
constexpr int ITEMS = 31;
constexpr int TILE  = TPB * ITEMS;   // 7936 elements per block
constexpr int GRID  = 1024;          // GRID*TILE = 8,126,464 >= 8,000,000
constexpr unsigned MAGIC = 0xC0DE600Du;   // != 0xAAAAAAAA ws-poison, != 0

// Clamp monoid: f(x) = min(max(x + A, B), C). compose(l, r) (l applied first):
//   A = Al + Ar;  B = max(Bl + Ar, Br);  C = min(max(Cl + Ar, Br), Cr)
// Affine monoid: f(x) = P*x + Q. compose(l, r): P = Pl*Pr; Q = Pr*Ql + Qr
//
// Deadlock-freedom WITHOUT cooperative launch: virtual block id from a global
// atomic ticket => vid order == block start order; started blocks never
// preempted; every block publishes BEFORE waiting; waits target only lower
// vids. (CUB decoupled-lookback argument.)
//
// Fence-free sync: all scratch traffic is relaxed agent-scope atomics (served
// at the coherence point, never cached stale). Producer orders data->flag->
// counter with s_waitcnt vmcnt(0). Consumer gate: ONE lane spins on the done
// counter (done >= b implies b publishes completed), then one 64-lane pass
// verifies the specific predecessor flags (rarely loops).

#define AT_LOAD(p)    __hip_atomic_load((p), __ATOMIC_RELAXED, __HIP_MEMORY_SCOPE_AGENT)
#define AT_STORE(p,v) __hip_atomic_store((p), (v), __ATOMIC_RELAXED, __HIP_MEMORY_SCOPE_AGENT)

__device__ __forceinline__ unsigned long long pack2(float a, float b) {
    union { float f[2]; unsigned long long u; } v; v.f[0] = a; v.f[1] = b; return v.u;
}
__device__ __forceinline__ float2 unpack2(unsigned long long u) {
    union { float f[2]; unsigned long long u; } v; v.u = u;
    return make_float2(v.f[0], v.f[1]);
}

__global__ __launch_bounds__(TPB, 4)
void awbm_kernel(const float* __restrict__ x,
                 const float* __restrict__ pBFI,
                 const float* __restrict__ pK,
                 const float* __restrict__ pSmax,
                 float* __restrict__ out,
                 float* __restrict__ ws,
                 int T)
{
    __shared__ __align__(16) float lds_d[TILE];
    __shared__ float sm3[12];    // phase-A wave aggregates (3 floats x 4 waves)
    __shared__ float sm2[8];     // phase-C wave aggregates (2 floats x 4 waves)
    __shared__ float bc[5];      // cross-block fold broadcast (3 clamp + 2 affine)
    __shared__ unsigned svid;

    const int tid  = threadIdx.x;
    const int lane = tid & 63;
    const int wv   = tid >> 6;

    // ws layout (bytes): [0,8K) scrAB1 ull[GRID] | [8K,12K) scrC1 f[GRID] |
    // [12K,20K) scrPQ2 ull[GRID] | [20K,24K) f1 u[GRID] | [24K,28K) f2 u[GRID] |
    // [28K,+12) ctrl {ticket, done1, done2}
    unsigned long long* scrAB1 = (unsigned long long*)ws;
    float*              scrC1  = (float*)((char*)ws + 8192);
    unsigned long long* scrPQ2 = (unsigned long long*)((char*)ws + 12288);
    unsigned*           f1     = (unsigned*)((char*)ws + 20480);
    unsigned*           f2     = (unsigned*)((char*)ws + 24576);
    unsigned*           ctrl   = (unsigned*)((char*)ws + 28672);

    if (tid == 0)
        svid = __hip_atomic_fetch_add(&ctrl[0], 1u, __ATOMIC_RELAXED, __HIP_MEMORY_SCOPE_AGENT);

    const float bfi  = pBFI[0];
    const float k    = pK[0];
    const float smax = pSmax[0];
    const float omb  = 1.0f - bfi;
    const float omk  = 1.0f - k;
    const float INF  = __builtin_inff();

    __syncthreads();   // S0: svid visible
    const int b     = (int)svid;
    const int gbase = b * TILE;

    // ---- stage x -> d in LDS (the ONLY read of x) ----
    {
        const float4* x4 = (const float4*)x;   // two (p,e) pairs per float4
        float2* d2 = (float2*)lds_d;
        for (int i = tid; i < TILE / 2; i += TPB) {
            int e = gbase + 2 * i;
            float2 dv; dv.x = 0.f; dv.y = 0.f;
            if (e < T) {                       // T even => pair fully in-range
                float4 v = x4[(gbase >> 1) + i];
                dv.x = v.x - v.y;
                dv.y = v.z - v.w;
            }
            d2[i] = dv;
        }
    }
    __syncthreads();   // S1

    const int toff = tid * ITEMS;
    int m = T - gbase - toff;
    m = m < 0 ? 0 : (m > ITEMS ? ITEMS : m);
    const bool full = (m == ITEMS);

    // ---- Phase A: per-thread clamp fold; d cached into registers (full path) ----
    float dreg[ITEMS];                         // reg-resident d, later partials
    float rA = 0.f, rB = -INF, rC = INF;
    if (full) {
#pragma unroll
        for (int j = 0; j < ITEMS; ++j) {
            float d = lds_d[toff + j];
            dreg[j] = d;
            rA += d;
            rB = fmaxf(rB + d, 0.f);
            rC = fminf(fmaxf(rC + d, 0.f), smax);
        }
    } else {
        for (int j = 0; j < m; ++j) {
            float d = lds_d[toff + j];
            rA += d;
            rB = fmaxf(rB + d, 0.f);
            rC = fminf(fmaxf(rC + d, 0.f), smax);
        }
    }
    // wave inclusive scan (shfl, no barriers)
#pragma unroll
    for (int s = 1; s < 64; s <<= 1) {
        float pA = __shfl_up(rA, s, 64), pB = __shfl_up(rB, s, 64), pC = __shfl_up(rC, s, 64);
        if (lane >= s) {
            float nA = pA + rA, nB = fmaxf(pB + rA, rB), nC = fminf(fmaxf(pC + rA, rB), rC);
            rA = nA; rB = nB; rC = nC;
        }
    }
    if (lane == 63) { sm3[wv * 3] = rA; sm3[wv * 3 + 1] = rB; sm3[wv * 3 + 2] = rC; }
    __syncthreads();   // S2
    float wA = 0.f, wB = -INF, wC = INF;       // exclusive cross-wave prefix
    for (int i = 0; i < wv; ++i) {
        float a = sm3[i * 3], bb = sm3[i * 3 + 1], c = sm3[i * 3 + 2];
        float nA = wA + a, nB = fmaxf(wB + a, bb), nC = fminf(fmaxf(wC + a, bb), c);
        wA = nA; wB = nB; wC = nC;
    }
    {   // thread inclusive across block
        float nA = wA + rA, nB = fmaxf(wB + rA, rB), nC = fminf(fmaxf(wC + rA, rB), rC);
        rA = nA; rB = nB; rC = nC;
    }
    if (tid == TPB - 1) {                      // publish: data -> flag -> counter
        AT_STORE(&scrAB1[b], pack2(rA, rB));
        AT_STORE(&scrC1[b], rC);
        __atomic_signal_fence(__ATOMIC_SEQ_CST);
        __builtin_amdgcn_s_waitcnt(0);
        __atomic_signal_fence(__ATOMIC_SEQ_CST);
        AT_STORE(&f1[b], MAGIC);
        __atomic_signal_fence(__ATOMIC_SEQ_CST);
        __builtin_amdgcn_s_waitcnt(0);
        __atomic_signal_fence(__ATOMIC_SEQ_CST);
        __hip_atomic_fetch_add(&ctrl[1], 1u, __ATOMIC_RELAXED, __HIP_MEMORY_SCOPE_AGENT);
    }
    // thread-exclusive in-block prefix
    float eA, eB, eC;
    {
        float pA = __shfl_up(rA, 1, 64), pB = __shfl_up(rB, 1, 64), pC = __shfl_up(rC, 1, 64);
        eA = (lane == 0) ? wA : pA;
        eB = (lane == 0) ? wB : pB;
        eC = (lane == 0) ? wC : pC;
    }

    // ---- cross-block clamp fold over [0,b): wave 0 only ----
    if (wv == 0) {
        if (lane == 0)
            while ((int)AT_LOAD(&ctrl[1]) < b) __builtin_amdgcn_s_sleep(2);
        // wave reconverges here: >= b publishes complete. Verify our flags.
        const int s0 = lane * 16;
        int cnt = b - s0; cnt = cnt < 0 ? 0 : (cnt > 16 ? 16 : cnt);
        unsigned pend = (cnt >= 16) ? 0xFFFFu : ((1u << cnt) - 1u);
        while (pend) {
            for (int j = 0; j < 16; ++j)
                if ((pend >> j) & 1u)
                    if (AT_LOAD(&f1[s0 + j]) == MAGIC) pend &= ~(1u << j);
            if (pend) __builtin_amdgcn_s_sleep(1);
        }
        __atomic_signal_fence(__ATOMIC_ACQUIRE);
        float cA = 0.f, cB = -INF, cC = INF;
        for (int j = 0; j < cnt; ++j) {
            float2 ab = unpack2(AT_LOAD(&scrAB1[s0 + j]));
            float  gc = AT_LOAD(&scrC1[s0 + j]);
            float nA = cA + ab.x, nB = fmaxf(cB + ab.x, ab.y), nC = fminf(fmaxf(cC + ab.x, ab.y), gc);
            cA = nA; cB = nB; cC = nC;
        }
#pragma unroll
        for (int s = 1; s < 64; s <<= 1) {     // ordered fold (contiguous chunks)
            float oa = __shfl_down(cA, s, 64), ob = __shfl_down(cB, s, 64), oc = __shfl_down(cC, s, 64);
            float nA = cA + oa, nB = fmaxf(cB + oa, ob), nC = fminf(fmaxf(cC + oa, ob), oc);
            cA = nA; cB = nB; cC = nC;
        }
        if (lane == 0) { bc[0] = cA; bc[1] = cB; bc[2] = cC; }
    }
    __syncthreads();   // S3
    float S;
    {
        S = fminf(fmaxf(0.5f + bc[0], bc[1]), bc[2]);  // S_INIT=0.5 -> block start
        S = fminf(fmaxf(S + eA, eB), eC);              // thread start
    }

    // ---- Phase C: sequential walk; partials into registers (full) / LDS (edge) ----
    float p = 1.f, c = 0.f;
    if (full) {
#pragma unroll
        for (int j = 0; j < ITEMS; ++j) {
            float d  = dreg[j];
            float S1 = fmaxf(S + d, 0.f);
            float ex = fmaxf(S1 - smax, 0.f);
            S = S1 - ex;
            float w = c + bfi * ex;
            dreg[j] = omb * ex + omk * w;      // partial outflow, reg-resident
            c = k * w;
            p *= k;
        }
    } else {
        for (int j = 0; j < m; ++j) {
            float d  = lds_d[toff + j];
            float S1 = fmaxf(S + d, 0.f);
            float ex = fmaxf(S1 - smax, 0.f);
            S = S1 - ex;
            float w = c + bfi * ex;
            lds_d[toff + j] = omb * ex + omk * w;
            c = k * w;
            p *= k;
        }
    }
    // wave inclusive affine scan
#pragma unroll
    for (int s = 1; s < 64; s <<= 1) {
        float pp = __shfl_up(p, s, 64), pc = __shfl_up(c, s, 64);
        if (lane >= s) {
            float nq = p * pc + c;   // Q = Pr*Ql + Qr
            p = pp * p;
            c = nq;
        }
    }
    if (lane == 63) { sm2[wv * 2] = p; sm2[wv * 2 + 1] = c; }
    __syncthreads();   // S4
    float wP = 1.f, wQ = 0.f;                  // exclusive cross-wave prefix
    for (int i = 0; i < wv; ++i) {
        float gp = sm2[i * 2], gq = sm2[i * 2 + 1];
        wQ = gp * wQ + gq;
        wP = wP * gp;
    }
    {   // thread inclusive across block
        float nq = p * wQ + c;
        p = wP * p;
        c = nq;
    }
    if (tid == TPB - 1) {                      // publish affine aggregate
        AT_STORE(&scrPQ2[b], pack2(p, c));
        __atomic_signal_fence(__ATOMIC_SEQ_CST);
        __builtin_amdgcn_s_waitcnt(0);
        __atomic_signal_fence(__ATOMIC_SEQ_CST);
        AT_STORE(&f2[b], MAGIC);
        __atomic_signal_fence(__ATOMIC_SEQ_CST);
        __builtin_amdgcn_s_waitcnt(0);
        __atomic_signal_fence(__ATOMIC_SEQ_CST);
        __hip_atomic_fetch_add(&ctrl[2], 1u, __ATOMIC_RELAXED, __HIP_MEMORY_SCOPE_AGENT);
    }
    float eP, eQ;
    {
        float pp = __shfl_up(p, 1, 64), pc = __shfl_up(c, 1, 64);
        eP = (lane == 0) ? wP : pp;
        eQ = (lane == 0) ? wQ : pc;
    }

    // ---- cross-block affine fold over [0,b): wave 0 only ----
    if (wv == 0) {
        if (lane == 0)
            while ((int)AT_LOAD(&ctrl[2]) < b) __builtin_amdgcn_s_sleep(2);
        const int s0 = lane * 16;
        int cnt = b - s0; cnt = cnt < 0 ? 0 : (cnt > 16 ? 16 : cnt);
        unsigned pend = (cnt >= 16) ? 0xFFFFu : ((1u << cnt) - 1u);
        while (pend) {
            for (int j = 0; j < 16; ++j)
                if ((pend >> j) & 1u)
                    if (AT_LOAD(&f2[s0 + j]) == MAGIC) pend &= ~(1u << j);
            if (pend) __builtin_amdgcn_s_sleep(1);
        }
        __atomic_signal_fence(__ATOMIC_ACQUIRE);
        float cP = 1.f, cQ = 0.f;
        for (int j = 0; j < cnt; ++j) {
            float2 pq = unpack2(AT_LOAD(&scrPQ2[s0 + j]));
            cQ = pq.x * cQ + pq.y;
            cP = cP * pq.x;
        }
#pragma unroll
        for (int s = 1; s < 64; s <<= 1) {     // ordered fold
            float op = __shfl_down(cP, s, 64), oq = __shfl_down(cQ, s, 64);
            float nq = op * cQ + oq;
            cP = cP * op;
            cQ = nq;
        }
        if (lane == 0) { bc[3] = cP; bc[4] = cQ; }
    }
    __syncthreads();   // S5
    float Bst;
    {
        Bst = bc[3] * 1.0f + bc[4];  // B_INIT = 1.0 -> B at block start
        Bst = eP * Bst + eQ;         // B at thread start
    }

    // ---- Phase E: add (1-k)*k^j*B_start; write regs -> LDS once ----
    float f = omk * Bst;
    if (full) {
#pragma unroll
        for (int j = 0; j < ITEMS; ++j) {
            lds_d[toff + j] = dreg[j] + f;
            f *= k;
        }
    } else {
        for (int j = 0; j < m; ++j) { lds_d[toff + j] += f; f *= k; }
    }
    __syncthreads();   // S6
    {
        float4* out4 = (float4*)out;
        const float4* l4 = (const float4*)lds_d;
        for (int i = tid; i < TILE / 4; i += TPB) {
            int e = gbase + 4 * i;
            if (e < T) out4[(gbase >> 2) + i] = l4[i];   // T%4==0
        }
    }
}

extern "C" void kernel_launch(void* const* d_in, const int* in_sizes, int n_in,
                              void* d_out, int out_size, void* d_ws, size_t ws_size,
                              hipStream_t stream) {
    const float* x    = (const float*)d_in[0];
    const float* BFI  = (const float*)d_in[1];
    const float* K    = (const float*)d_in[2];
    const float* Smax = (const float*)d_in[3];
    float* out = (float*)d_out;
    float* ws  = (float*)d_ws;   // needs 28 KB + 12 B
    int T = out_size;            // 8,000,000

    // zero ticket + done1 + done2 (ws is poisoned 0xAA before every replay;
    // flags poll for MAGIC so poison is a valid "not ready" state).
    hipMemsetAsync((char*)d_ws + 28672, 0, 12, stream);
    awbm_kernel<<<dim3(GRID), dim3(TPB), 0, stream>>>(x, BFI, K, Smax, out, ws, T);
}

// Round 6
// 127.457 us; speedup vs baseline: 1.8027x; 1.8027x over previous
//
#include <hip/hip_runtime.h>

constexpr int TPB   = 256;
constexpr int ITEMS = 31;
constexpr int TILE  = TPB * ITEMS;   // 7936 elements per block
constexpr int GRID  = 1024;          // GRID*TILE = 8,126,464 >= 8,000,000
constexpr unsigned MAGIC = 0xC0DE600Du;   // != 0xAAAAAAAA ws-poison, != 0

// Clamp monoid: f(x) = min(max(x + A, B), C). compose(l, r) (l applied first):
//   A = Al + Ar;  B = max(Bl + Ar, Br);  C = min(max(Cl + Ar, Br), Cr)
// Constant map <=> B == C, value C (min applied last).
// Affine monoid: f(x) = P*x + Q. compose(l, r): P = Pl*Pr; Q = Pr*Ql + Qr.
//
// Cross-block propagation is SINGLE-HOP (not full decoupled lookback):
//  * S-gate: walk back composing predecessor clamp maps until the composition
//    is constant (B>=C) -> S_blockstart = C. Random-walk data saturates every
//    block, so expected hops = 1. Exact (runtime-verified), any data.
//  * B-gate: B_start(b) = sum_j accP*Q_{b-1-j} with accP = prod P; P_block =
//    k^7936 (~0 for benched k=0.5), walk truncates at accP < 1e-35 -> 1 hop.
//    Error <= 1e-35*|B|, vs 1.8e-2 threshold.
// Deadlock-freedom: ticket => vid order == start order; publish-before-wait;
// waits target only lower vids (CUB decoupled-lookback argument).
// Fence-free sync: scratch = relaxed agent-scope atomics (coherence point,
// never stale); producer orders data->flag with s_waitcnt vmcnt(0).

#define AT_LOAD(p)    __hip_atomic_load((p), __ATOMIC_RELAXED, __HIP_MEMORY_SCOPE_AGENT)
#define AT_STORE(p,v) __hip_atomic_store((p), (v), __ATOMIC_RELAXED, __HIP_MEMORY_SCOPE_AGENT)

__global__ __launch_bounds__(TPB, 4)
void awbm_kernel(const float* __restrict__ x,
                 const float* __restrict__ pBFI,
                 const float* __restrict__ pK,
                 const float* __restrict__ pSmax,
                 float* __restrict__ out,
                 float* __restrict__ ws,
                 int T)
{
    __shared__ __align__(16) float lds_d[TILE];
    __shared__ float sm3[12];    // phase-A wave aggregates (3 x 4 waves)
    __shared__ float sm2[8];     // phase-C wave aggregates (2 x 4 waves)
    __shared__ float bc[2];      // bc[0] = S at block start, bc[1] = B at block start
    __shared__ unsigned svid;

    const int tid  = threadIdx.x;
    const int lane = tid & 63;
    const int wv   = tid >> 6;

    // ws layout: 5 float[GRID] scratch + 2 unsigned[GRID] flags + ticket
    float*    scrA   = ws;
    float*    scrB   = ws + GRID;
    float*    scrC   = ws + 2 * GRID;
    float*    scrP   = ws + 3 * GRID;
    float*    scrQ   = ws + 4 * GRID;
    unsigned* f1     = (unsigned*)(ws + 5 * GRID);
    unsigned* f2     = (unsigned*)(ws + 6 * GRID);
    unsigned* ticket = (unsigned*)(ws + 7 * GRID);

    if (tid == 0)
        svid = __hip_atomic_fetch_add(ticket, 1u, __ATOMIC_RELAXED, __HIP_MEMORY_SCOPE_AGENT);

    const float bfi  = pBFI[0];
    const float k    = pK[0];
    const float smax = pSmax[0];
    const float omb  = 1.0f - bfi;
    const float omk  = 1.0f - k;
    const float INF  = __builtin_inff();

    __syncthreads();   // S0: svid visible
    const int b     = (int)svid;
    const int gbase = b * TILE;

    // ---- stage x -> d in LDS (the ONLY read of x) ----
    {
        const float4* x4 = (const float4*)x;   // two (p,e) pairs per float4
        float2* d2 = (float2*)lds_d;
        for (int i = tid; i < TILE / 2; i += TPB) {
            int e = gbase + 2 * i;
            float2 dv; dv.x = 0.f; dv.y = 0.f;
            if (e < T) {                       // T even => pair fully in-range
                float4 v = x4[(gbase >> 1) + i];
                dv.x = v.x - v.y;
                dv.y = v.z - v.w;
            }
            d2[i] = dv;
        }
    }
    __syncthreads();   // S1

    const int toff = tid * ITEMS;
    int m = T - gbase - toff;
    m = m < 0 ? 0 : (m > ITEMS ? ITEMS : m);

    // ---- Phase A: per-thread clamp fold ----
    float rA = 0.f, rB = -INF, rC = INF;
    if (m == ITEMS) {
#pragma unroll
        for (int j = 0; j < ITEMS; ++j) {
            float d = lds_d[toff + j];
            rA += d;
            rB = fmaxf(rB + d, 0.f);
            rC = fminf(fmaxf(rC + d, 0.f), smax);
        }
    } else {
        for (int j = 0; j < m; ++j) {
            float d = lds_d[toff + j];
            rA += d;
            rB = fmaxf(rB + d, 0.f);
            rC = fminf(fmaxf(rC + d, 0.f), smax);
        }
    }
    // wave inclusive scan (shfl, no barriers)
#pragma unroll
    for (int s = 1; s < 64; s <<= 1) {
        float pA = __shfl_up(rA, s, 64), pB = __shfl_up(rB, s, 64), pC = __shfl_up(rC, s, 64);
        if (lane >= s) {
            float nA = pA + rA, nB = fmaxf(pB + rA, rB), nC = fminf(fmaxf(pC + rA, rB), rC);
            rA = nA; rB = nB; rC = nC;
        }
    }
    if (lane == 63) { sm3[wv * 3] = rA; sm3[wv * 3 + 1] = rB; sm3[wv * 3 + 2] = rC; }
    __syncthreads();   // S2
    float wA = 0.f, wB = -INF, wC = INF;       // exclusive cross-wave prefix
    for (int i = 0; i < wv; ++i) {
        float a = sm3[i * 3], bb = sm3[i * 3 + 1], c = sm3[i * 3 + 2];
        float nA = wA + a, nB = fmaxf(wB + a, bb), nC = fminf(fmaxf(wC + a, bb), c);
        wA = nA; wB = nB; wC = nC;
    }
    {   // thread inclusive across block
        float nA = wA + rA, nB = fmaxf(wB + rA, rB), nC = fminf(fmaxf(wC + rA, rB), rC);
        rA = nA; rB = nB; rC = nC;
    }
    if (tid == TPB - 1) {                      // publish: data -> vmcnt(0) -> flag
        AT_STORE(&scrA[b], rA); AT_STORE(&scrB[b], rB); AT_STORE(&scrC[b], rC);
        __atomic_signal_fence(__ATOMIC_SEQ_CST);
        __builtin_amdgcn_s_waitcnt(0);
        __atomic_signal_fence(__ATOMIC_SEQ_CST);
        AT_STORE(&f1[b], MAGIC);
    }
    // thread-exclusive in-block prefix
    float eA, eB, eC;
    {
        float pA = __shfl_up(rA, 1, 64), pB = __shfl_up(rB, 1, 64), pC = __shfl_up(rC, 1, 64);
        eA = (lane == 0) ? wA : pA;
        eB = (lane == 0) ? wB : pB;
        eC = (lane == 0) ? wC : pC;
    }

    // ---- S-gate: backward walk until composed map is constant (1 hop exp.) ----
    if (tid == 0) {
        float aA = 0.f, aB = -INF, aC = INF;   // identity suffix map
        float Sst;
        int j = b - 1;
        for (;;) {
            if (j < 0) { Sst = fminf(fmaxf(0.5f + aA, aB), aC); break; }  // S_INIT
            while (AT_LOAD(&f1[j]) != MAGIC) __builtin_amdgcn_s_sleep(1);
            __atomic_signal_fence(__ATOMIC_ACQUIRE);
            float Aj = AT_LOAD(&scrA[j]), Bj = AT_LOAD(&scrB[j]), Cj = AT_LOAD(&scrC[j]);
            // acc' = acc o F_j (F_j applied first)
            float nA = Aj + aA, nB = fmaxf(Bj + aA, aB), nC = fminf(fmaxf(Cj + aA, aB), aC);
            aA = nA; aB = nB; aC = nC;
            if (aB >= aC) { Sst = aC; break; } // constant map: earlier blocks irrelevant
            --j;
        }
        bc[0] = Sst;
    }
    __syncthreads();   // S3
    float S = fminf(fmaxf(bc[0] + eA, eB), eC);   // S at thread start

    // ---- Phase C: sequential walk; partial outflow into LDS; affine fold ----
    float p = 1.f, c = 0.f;
    if (m == ITEMS) {
#pragma unroll
        for (int j = 0; j < ITEMS; ++j) {
            float d  = lds_d[toff + j];
            float S1 = fmaxf(S + d, 0.f);
            float ex = fmaxf(S1 - smax, 0.f);
            S = S1 - ex;
            float w = c + bfi * ex;
            lds_d[toff + j] = omb * ex + omk * w;
            c = k * w;
            p *= k;
        }
    } else {
        for (int j = 0; j < m; ++j) {
            float d  = lds_d[toff + j];
            float S1 = fmaxf(S + d, 0.f);
            float ex = fmaxf(S1 - smax, 0.f);
            S = S1 - ex;
            float w = c + bfi * ex;
            lds_d[toff + j] = omb * ex + omk * w;
            c = k * w;
            p *= k;
        }
    }
    // wave inclusive affine scan
#pragma unroll
    for (int s = 1; s < 64; s <<= 1) {
        float pp = __shfl_up(p, s, 64), pc = __shfl_up(c, s, 64);
        if (lane >= s) {
            float nq = p * pc + c;   // Q = Pr*Ql + Qr
            p = pp * p;
            c = nq;
        }
    }
    if (lane == 63) { sm2[wv * 2] = p; sm2[wv * 2 + 1] = c; }
    __syncthreads();   // S4
    float wP = 1.f, wQ = 0.f;                  // exclusive cross-wave prefix
    for (int i = 0; i < wv; ++i) {
        float gp = sm2[i * 2], gq = sm2[i * 2 + 1];
        wQ = gp * wQ + gq;
        wP = wP * gp;
    }
    {   // thread inclusive across block
        float nq = p * wQ + c;
        p = wP * p;
        c = nq;
    }
    if (tid == TPB - 1) {                      // publish block-local (P,Q)
        AT_STORE(&scrP[b], p); AT_STORE(&scrQ[b], c);
        __atomic_signal_fence(__ATOMIC_SEQ_CST);
        __builtin_amdgcn_s_waitcnt(0);
        __atomic_signal_fence(__ATOMIC_SEQ_CST);
        AT_STORE(&f2[b], MAGIC);
    }
    float eP, eQ;
    {
        float pp = __shfl_up(p, 1, 64), pc = __shfl_up(c, 1, 64);
        eP = (lane == 0) ? wP : pp;
        eQ = (lane == 0) ? wQ : pc;
    }

    // ---- B-gate: backward walk, truncated by k-power decay (1 hop exp.) ----
    if (tid == 0) {
        float accP = 1.f, Bst = 0.f;
        int j = b - 1;
        for (;;) {
            if (j < 0) { Bst += accP * 1.0f; break; }   // B_INIT = 1.0
            if (accP < 1e-35f) break;                   // fully decayed
            while (AT_LOAD(&f2[j]) != MAGIC) __builtin_amdgcn_s_sleep(1);
            __atomic_signal_fence(__ATOMIC_ACQUIRE);
            float Pj = AT_LOAD(&scrP[j]), Qj = AT_LOAD(&scrQ[j]);
            Bst  += accP * Qj;
            accP *= Pj;
            --j;
        }
        bc[1] = Bst;
    }
    __syncthreads();   // S5
    float Bst = eP * bc[1] + eQ;               // B at thread start

    // ---- Phase E: add (1-k)*k^j*B_start, coalesced store ----
    float f = omk * Bst;
    if (m == ITEMS) {
#pragma unroll
        for (int j = 0; j < ITEMS; ++j) { lds_d[toff + j] += f; f *= k; }
    } else {
        for (int j = 0; j < m; ++j) { lds_d[toff + j] += f; f *= k; }
    }
    __syncthreads();   // S6
    {
        float4* out4 = (float4*)out;
        const float4* l4 = (const float4*)lds_d;
        for (int i = tid; i < TILE / 4; i += TPB) {
            int e = gbase + 4 * i;
            if (e < T) out4[(gbase >> 2) + i] = l4[i];   // T%4==0
        }
    }
}

extern "C" void kernel_launch(void* const* d_in, const int* in_sizes, int n_in,
                              void* d_out, int out_size, void* d_ws, size_t ws_size,
                              hipStream_t stream) {
    const float* x    = (const float*)d_in[0];
    const float* BFI  = (const float*)d_in[1];
    const float* K    = (const float*)d_in[2];
    const float* Smax = (const float*)d_in[3];
    float* out = (float*)d_out;
    float* ws  = (float*)d_ws;   // needs 28 KB + 4 B
    int T = out_size;            // 8,000,000

    // zero only the ticket (flags poll for MAGIC, so 0xAA poison is "not ready")
    hipMemsetAsync((char*)d_ws + 7 * GRID * sizeof(float), 0, sizeof(unsigned), stream);
    awbm_kernel<<<dim3(GRID), dim3(TPB), 0, stream>>>(x, BFI, K, Smax, out, ws, T);
}